// Round 6
// baseline (11222.740 us; speedup 1.0000x reference)
//
#include <hip/hip_runtime.h>

#define H 256
#define T_STEPS 128
#define B_BATCH 256
#define I_LDS 48      // WhhT rows [0,48) persistent in LDS (48*768*4B = 147456 B)
#define XS_STR 20     // words per 16-float xs group: bank-spread, 16B-aligned

__device__ __forceinline__ float sigmoidf_(float x) { return 1.0f / (1.0f + expf(-x)); }

#define PICK(V_, C_) ((C_) == 0 ? (V_).x : (C_) == 1 ? (V_).y : (C_) == 2 ? (V_).z : (V_).w)

// ---------------- prep kernels (tiny, once per launch) ----------------

__global__ void prep_weff(const float* __restrict__ W1, const float* __restrict__ W2,
                          const float* __restrict__ b1, const float* __restrict__ b2,
                          float* __restrict__ Weff, float* __restrict__ beff) {
    int i = blockIdx.x, j = threadIdx.x;
    const float* w2row = W2 + j * H;
    float acc = 0.f;
    for (int d = 0; d < H; ++d) acc += W1[d * H + i] * w2row[d];
    Weff[i * H + j] = acc;
    if (i == 0) {
        float bacc = b2[j];
        for (int d = 0; d < H; ++d) bacc += b1[d] * w2row[d];
        beff[j] = bacc;
    }
}

__global__ void prep_whht(const float* __restrict__ Whh, float* __restrict__ WhhT) {
    int idx = blockIdx.x * blockDim.x + threadIdx.x;  // 196608
    int i = idx / 768;
    int r = idx - i * 768;
    WhhT[idx] = Whh[r * H + i];
}

__global__ void prep_wo(const float* __restrict__ Wo1, const float* __restrict__ Wo2,
                        const float* __restrict__ bo1, const float* __restrict__ bo2,
                        float* __restrict__ wo, float* __restrict__ bo) {
    int i = threadIdx.x;
    float acc = 0.f;
    for (int d = 0; d < H; ++d) acc += Wo1[d * H + i] * Wo2[d];
    wo[i] = acc;
    float p = bo1[i] * Wo2[i];
    __shared__ float red[4];
    for (int off = 32; off > 0; off >>= 1) p += __shfl_down(p, off);
    if ((i & 63) == 0) red[i >> 6] = p;
    __syncthreads();
    if (i == 0) bo[0] = red[0] + red[1] + red[2] + red[3] + bo2[0];
}

// ---------------- main scan: 1 block (1024 thr) per batch row ----------------
// tid = jt*16 + ks.  jt in [0,64): owns output tile cols 4jt..4jt+3.
// ks in [0,16): K-slice rows [16ks,16ks+16).  c = ks&3: the ONE column this
// lane finalizes (tanh/gates/h for col 4jt+c; 4-fold replicated over ks).
// Weights: 16 float4 (Weff rows of K-slice x 4 cols) pinned in regs/AGPRs.
// Partials combined with a 16-lane shfl_xor tree -> no LDS part[], no
// gh_lds, no block reduce.  gh (3 gates x 4 cols) + out-head dot ride the
// same decomposition.  All math f32 (f16 diverges, round 2).

__global__ __attribute__((amdgpu_flat_work_group_size(1024, 1024),
                          amdgpu_waves_per_eu(4, 4)))
void ode_rnn_main(
    const float* __restrict__ b_in, const float* __restrict__ m_in,
    const float* __restrict__ trm_in, const float* __restrict__ tem_in,
    const float* __restrict__ h0,
    const float* __restrict__ Weff, const float* __restrict__ beff,
    const float* __restrict__ WhhT,
    const float* __restrict__ W_ih, const float* __restrict__ b_ih,
    const float* __restrict__ b_hh,
    const float* __restrict__ wo, const float* __restrict__ bo_p,
    float* __restrict__ out)
{
    const int tid = threadIdx.x;
    const int bb  = blockIdx.x;
    const int jt  = tid >> 4;
    const int ks  = tid & 15;
    const int c   = ks & 3;
    const int jc  = 4 * jt + c;

    __shared__ float whh_lds[I_LDS * 768];                 // 147456 B
    __shared__ __align__(16) float xsb[2][16 * XS_STR];    // 2560 B
    __shared__ __align__(16) float wo_lds[16 * XS_STR];    // 1280 B
    __shared__ float times_s[T_STEPS];
    __shared__ float bv_s[T_STEPS], trm_s[T_STEPS], tem_s[T_STEPS], m_s[T_STEPS];

    // Weff tile: rows 16ks..16ks+15 x cols 4jt..4jt+3, pinned
    float4 wregv[16];
    #pragma unroll
    for (int il = 0; il < 16; ++il)
        wregv[il] = *(const float4*)&Weff[(16 * ks + il) * H + 4 * jt];
    #pragma unroll
    for (int il = 0; il < 16; ++il)
        asm volatile("" : "+v"(wregv[il].x), "+v"(wregv[il].y),
                          "+v"(wregv[il].z), "+v"(wregv[il].w));

    // stage WhhT rows [0,I_LDS) + wo (padded) + per-step scalars
    for (int k = tid; k < I_LDS * 768; k += 1024) whh_lds[k] = WhhT[k];
    if (tid < H) wo_lds[(tid >> 4) * XS_STR + (tid & 15)] = wo[tid];
    if (tid < T_STEPS) {
        times_s[tid] = b_in[2 * tid];   // times identical across batch
        int bt = bb * T_STEPS + tid;
        bv_s[tid]  = b_in[2 * bt + 1];
        trm_s[tid] = trm_in[bt];
        tem_s[tid] = tem_in[bt];
        m_s[tid]   = m_in[bt];
    }

    float h = h0[bb * H + jc];
    const float be   = beff[jc];
    const float bihr = b_ih[jc], bihz = b_ih[H + jc], bihn = b_ih[2 * H + jc];
    const float bhhr = b_hh[jc], bhhz = b_hh[H + jc], bhhn = b_hh[2 * H + jc];
    const float wihr = W_ih[jc], wihz = W_ih[H + jc], wihn = W_ih[2 * H + jc];
    const float bo   = bo_p[0];

    const int pubidx = (jt >> 2) * XS_STR + 4 * (jt & 3);  // + c at write time

    if (ks < 4) xsb[0][pubidx + ks] = h;   // ks==c for ks<4
    __syncthreads();

    int cur = 0;

    #define EV_FMA(XI_, IL_)                                     \
        a_.x = fmaf((XI_), wregv[IL_].x, a_.x);                  \
        a_.y = fmaf((XI_), wregv[IL_].y, a_.y);                  \
        a_.z = fmaf((XI_), wregv[IL_].z, a_.z);                  \
        a_.w = fmaf((XI_), wregv[IL_].w, a_.w);

    // eval: 4 LDS float4 reads, 64 FMA, 16-lane xor-reduce, pick own column
    #define EVAL(SUM_) do {                                      \
        const float* xp_ = &xsb[cur][ks * XS_STR];               \
        float4 x0_ = *(const float4*)(xp_);                      \
        float4 x1_ = *(const float4*)(xp_ + 4);                  \
        float4 x2_ = *(const float4*)(xp_ + 8);                  \
        float4 x3_ = *(const float4*)(xp_ + 12);                 \
        float4 a_ = {0.f, 0.f, 0.f, 0.f};                        \
        EV_FMA(x0_.x, 0)  EV_FMA(x0_.y, 1)                       \
        EV_FMA(x0_.z, 2)  EV_FMA(x0_.w, 3)                       \
        EV_FMA(x1_.x, 4)  EV_FMA(x1_.y, 5)                       \
        EV_FMA(x1_.z, 6)  EV_FMA(x1_.w, 7)                       \
        EV_FMA(x2_.x, 8)  EV_FMA(x2_.y, 9)                       \
        EV_FMA(x2_.z, 10) EV_FMA(x2_.w, 11)                      \
        EV_FMA(x3_.x, 12) EV_FMA(x3_.y, 13)                      \
        EV_FMA(x3_.z, 14) EV_FMA(x3_.w, 15)                      \
        _Pragma("unroll")                                        \
        for (int o_ = 1; o_ < 16; o_ <<= 1) {                    \
            a_.x += __shfl_xor(a_.x, o_);                        \
            a_.y += __shfl_xor(a_.y, o_);                        \
            a_.z += __shfl_xor(a_.z, o_);                        \
            a_.w += __shfl_xor(a_.w, o_);                        \
        }                                                        \
        SUM_ = PICK(a_, c);                                      \
    } while (0)

    // publish next matvec arg (lanes ks<4, one b32 each); barrier; flip
    #define PUBLISH(V_) do {                                     \
        if (ks < 4) xsb[cur ^ 1][pubidx + ks] = (V_);            \
        __syncthreads();                                         \
        cur ^= 1;                                                \
    } while (0)

    // gh inner body over one K-slice from weight base WP_ (stride 768)
    #define GH_STEP(XI_, IL_, WP_) do {                          \
        const float* wl_ = (WP_) + (IL_) * 768;                  \
        float4 wr_ = *(const float4*)(wl_);                      \
        float4 wz_ = *(const float4*)(wl_ + 256);                \
        float4 wn_ = *(const float4*)(wl_ + 512);                \
        gr_.x = fmaf((XI_), wr_.x, gr_.x);                       \
        gr_.y = fmaf((XI_), wr_.y, gr_.y);                       \
        gr_.z = fmaf((XI_), wr_.z, gr_.z);                       \
        gr_.w = fmaf((XI_), wr_.w, gr_.w);                       \
        gz_.x = fmaf((XI_), wz_.x, gz_.x);                       \
        gz_.y = fmaf((XI_), wz_.y, gz_.y);                       \
        gz_.z = fmaf((XI_), wz_.z, gz_.z);                       \
        gz_.w = fmaf((XI_), wz_.w, gz_.w);                       \
        gn_.x = fmaf((XI_), wn_.x, gn_.x);                       \
        gn_.y = fmaf((XI_), wn_.y, gn_.y);                       \
        gn_.z = fmaf((XI_), wn_.z, gn_.z);                       \
        gn_.w = fmaf((XI_), wn_.w, gn_.w);                       \
    } while (0)

    #define GH_ALL(WBASE_)                                       \
        GH_STEP(x0_.x, 0,  WBASE_); GH_STEP(x0_.y, 1,  WBASE_);  \
        GH_STEP(x0_.z, 2,  WBASE_); GH_STEP(x0_.w, 3,  WBASE_);  \
        GH_STEP(x1_.x, 4,  WBASE_); GH_STEP(x1_.y, 5,  WBASE_);  \
        GH_STEP(x1_.z, 6,  WBASE_); GH_STEP(x1_.w, 7,  WBASE_);  \
        GH_STEP(x2_.x, 8,  WBASE_); GH_STEP(x2_.y, 9,  WBASE_);  \
        GH_STEP(x2_.z, 10, WBASE_); GH_STEP(x2_.w, 11, WBASE_);  \
        GH_STEP(x3_.x, 12, WBASE_); GH_STEP(x3_.y, 13, WBASE_);  \
        GH_STEP(x3_.z, 14, WBASE_); GH_STEP(x3_.w, 15, WBASE_);

    float tprev = 0.f;
    #pragma unroll 1
    for (int t = 0; t < T_STEPS; ++t) {
        float t1 = times_s[t];
        float dt = (t1 - tprev) * 0.5f;   // per-substep dt (N_SUB=2)
        tprev = t1;

        #pragma unroll
        for (int s = 0; s < 2; ++s) {
            float s1, s2, s3, s4;
            EVAL(s1); float k1 = tanhf(be + s1); PUBLISH(fmaf(0.5f * dt, k1, h));
            EVAL(s2); float k2 = tanhf(be + s2); PUBLISH(fmaf(0.5f * dt, k2, h));
            EVAL(s3); float k3 = tanhf(be + s3); PUBLISH(fmaf(dt, k3, h));
            EVAL(s4); float k4 = tanhf(be + s4);
            h = fmaf(dt * (1.f / 6.f), k1 + 2.f * (k2 + k3) + k4, h);
            PUBLISH(h);   // s=0: next substep's k1; s=1: hp for gh
        }

        // ---- gh (3 gates x 4 cols) + out-head, on hp in xsb[cur] ----
        {
            const float* xp_ = &xsb[cur][ks * XS_STR];
            float4 x0_ = *(const float4*)(xp_);
            float4 x1_ = *(const float4*)(xp_ + 4);
            float4 x2_ = *(const float4*)(xp_ + 8);
            float4 x3_ = *(const float4*)(xp_ + 12);
            float4 gr_ = {0.f, 0.f, 0.f, 0.f};
            float4 gz_ = {0.f, 0.f, 0.f, 0.f};
            float4 gn_ = {0.f, 0.f, 0.f, 0.f};

            if (ks < 3) {       // K-slice rows < 48: LDS-resident weights
                const float* wb_ = &whh_lds[(16 * ks) * 768 + 4 * jt];
                GH_ALL(wb_);
            } else {            // streamed from L2
                const float* wb_ = &WhhT[(16 * ks) * 768 + 4 * jt];
                GH_ALL(wb_);
            }

            // out-head partial on the same hp slice
            const float* wop_ = &wo_lds[ks * XS_STR];
            float4 w0_ = *(const float4*)(wop_);
            float4 w1_ = *(const float4*)(wop_ + 4);
            float4 w2_ = *(const float4*)(wop_ + 8);
            float4 w3_ = *(const float4*)(wop_ + 12);
            float p_ = x0_.x * w0_.x + x0_.y * w0_.y + x0_.z * w0_.z + x0_.w * w0_.w
                     + x1_.x * w1_.x + x1_.y * w1_.y + x1_.z * w1_.z + x1_.w * w1_.w
                     + x2_.x * w2_.x + x2_.y * w2_.y + x2_.z * w2_.z + x2_.w * w2_.w
                     + x3_.x * w3_.x + x3_.y * w3_.y + x3_.z * w3_.z + x3_.w * w3_.w;

            #pragma unroll
            for (int o_ = 1; o_ < 16; o_ <<= 1) {
                gr_.x += __shfl_xor(gr_.x, o_);
                gr_.y += __shfl_xor(gr_.y, o_);
                gr_.z += __shfl_xor(gr_.z, o_);
                gr_.w += __shfl_xor(gr_.w, o_);
                gz_.x += __shfl_xor(gz_.x, o_);
                gz_.y += __shfl_xor(gz_.y, o_);
                gz_.z += __shfl_xor(gz_.z, o_);
                gz_.w += __shfl_xor(gz_.w, o_);
                gn_.x += __shfl_xor(gn_.x, o_);
                gn_.y += __shfl_xor(gn_.y, o_);
                gn_.z += __shfl_xor(gn_.z, o_);
                gn_.w += __shfl_xor(gn_.w, o_);
                p_ += __shfl_xor(p_, o_);
            }

            float outv = tanhf(p_ + bo);
            float ghr = PICK(gr_, c) + bhhr;
            float ghz = PICK(gz_, c) + bhhz;
            float ghn = PICK(gn_, c) + bhhn;

            float bv = bv_s[t], trm = trm_s[t], tem = tem_s[t], mv = m_s[t];
            float x1v = bv * trm, x2v = outv * tem;

            float r1 = sigmoidf_(fmaf(x1v, wihr, bihr) + ghr);
            float z1 = sigmoidf_(fmaf(x1v, wihz, bihz) + ghz);
            float n1 = tanhf(fmaf(x1v, wihn, bihn) + r1 * ghn);
            float h1 = (1.f - z1) * n1 + z1 * h;

            float r2 = sigmoidf_(fmaf(x2v, wihr, bihr) + ghr);
            float z2 = sigmoidf_(fmaf(x2v, wihz, bihz) + ghz);
            float n2 = tanhf(fmaf(x2v, wihn, bihn) + r2 * ghn);
            float h2 = (1.f - z2) * n2 + z2 * h;

            if (tid == 0) out[bb * T_STEPS + t] = outv;
            h = trm * h1 + tem * h2 + (1.f - mv) * h;
        }

        PUBLISH(h);   // next step's k1 argument
    }
    #undef EVAL
    #undef PUBLISH
    #undef EV_FMA
    #undef GH_STEP
    #undef GH_ALL
}

// ---------------- launcher ----------------

extern "C" void kernel_launch(void* const* d_in, const int* in_sizes, int n_in,
                              void* d_out, int out_size, void* d_ws, size_t ws_size,
                              hipStream_t stream) {
    const float* b_in = (const float*)d_in[0];
    const float* m_in = (const float*)d_in[1];
    const float* trm  = (const float*)d_in[2];
    const float* tem  = (const float*)d_in[3];
    const float* h0   = (const float*)d_in[4];
    const float* W1   = (const float*)d_in[5];
    const float* b1   = (const float*)d_in[6];
    const float* W2   = (const float*)d_in[7];
    const float* b2   = (const float*)d_in[8];
    const float* W_ih = (const float*)d_in[9];
    const float* W_hh = (const float*)d_in[10];
    const float* b_ih = (const float*)d_in[11];
    const float* b_hh = (const float*)d_in[12];
    const float* Wo1  = (const float*)d_in[13];
    const float* bo1  = (const float*)d_in[14];
    const float* Wo2  = (const float*)d_in[15];
    const float* bo2  = (const float*)d_in[16];

    float* ws   = (float*)d_ws;
    float* Weff = ws;             // 65536
    float* beff = Weff + 65536;   // 256
    float* WhhT = beff + 256;     // 196608
    float* wo   = WhhT + 196608;  // 256
    float* bo   = wo + 256;       // 1

    prep_weff<<<256, 256, 0, stream>>>(W1, W2, b1, b2, Weff, beff);
    prep_whht<<<192, 1024, 0, stream>>>(W_hh, WhhT);
    prep_wo<<<1, 256, 0, stream>>>(Wo1, Wo2, bo1, bo2, wo, bo);

    ode_rnn_main<<<B_BATCH, 1024, 0, stream>>>(b_in, m_in, trm, tem, h0,
                                               Weff, beff, WhhT,
                                               W_ih, b_ih, b_hh, wo, bo,
                                               (float*)d_out);
}

// Round 7
// 2168.938 us; speedup vs baseline: 5.1743x; 5.1743x over previous
//
#include <hip/hip_runtime.h>

#define H 256
#define T_STEPS 128
#define B_BATCH 256
#define I_LDS 48      // WhhT rows [0,48) persistent in LDS (48*768*4B = 147456 B)
#define XGRP 36       // words per 32-float xs segment: 8 segments hit disjoint bank-quads

__device__ __forceinline__ float sigmoidf_(float x) { return 1.0f / (1.0f + expf(-x)); }

// ---------------- prep kernels (tiny, once per launch) ----------------

__global__ void prep_weff(const float* __restrict__ W1, const float* __restrict__ W2,
                          const float* __restrict__ b1, const float* __restrict__ b2,
                          float* __restrict__ Weff, float* __restrict__ beff) {
    int i = blockIdx.x, j = threadIdx.x;
    const float* w2row = W2 + j * H;
    float acc = 0.f;
    for (int d = 0; d < H; ++d) acc += W1[d * H + i] * w2row[d];
    Weff[i * H + j] = acc;
    if (i == 0) {
        float bacc = b2[j];
        for (int d = 0; d < H; ++d) bacc += b1[d] * w2row[d];
        beff[j] = bacc;
    }
}

__global__ void prep_whht(const float* __restrict__ Whh, float* __restrict__ WhhT) {
    int idx = blockIdx.x * blockDim.x + threadIdx.x;  // 196608
    int i = idx / 768;
    int r = idx - i * 768;
    WhhT[idx] = Whh[r * H + i];
}

__global__ void prep_wo(const float* __restrict__ Wo1, const float* __restrict__ Wo2,
                        const float* __restrict__ bo1, const float* __restrict__ bo2,
                        float* __restrict__ wo, float* __restrict__ bo) {
    int i = threadIdx.x;
    float acc = 0.f;
    for (int d = 0; d < H; ++d) acc += Wo1[d * H + i] * Wo2[d];
    wo[i] = acc;
    float p = bo1[i] * Wo2[i];
    __shared__ float red[4];
    for (int off = 32; off > 0; off >>= 1) p += __shfl_down(p, off);
    if ((i & 63) == 0) red[i >> 6] = p;
    __syncthreads();
    if (i == 0) bo[0] = red[0] + red[1] + red[2] + red[3] + bo2[0];
}

// ---------------- main scan: 1 block (1024 thr) per batch row ----------------
// tid = jp*8 + e.  jp in [0,128): owns column pair {2jp, 2jp+1}.
// e in [0,8): K-slice rows [32e, 32e+32).  c = e&1: the column this lane
// finalizes (jc = 2jp+c; 4-fold replicated over e).  Each thread holds
// 32 float2 Weff weights (rows of its K-slice x 2 cols), asm-pinned
// (remat-proof; round 4).  EVAL: 8 x ds_read_b128 where the 8 e-groups
// read 8 DISTINCT segments (stride XGRP=36 words -> disjoint bank-quads)
// and the 8 lanes within a group broadcast the same address -> near-free
// LDS reads vs round 5's 64 distinct floats/thread.  Reduce = 3-level
// shfl_xor over the 8-lane group.  gh phase = round 5's exact
// conflict-free code (round 6's tiled gh spilled regs + 16-way conflicts).
// All math f32 (f16 diverges, round 2).

__global__ __attribute__((amdgpu_flat_work_group_size(1024, 1024),
                          amdgpu_waves_per_eu(4, 4)))
void ode_rnn_main(
    const float* __restrict__ b_in, const float* __restrict__ m_in,
    const float* __restrict__ trm_in, const float* __restrict__ tem_in,
    const float* __restrict__ h0,
    const float* __restrict__ Weff, const float* __restrict__ beff,
    const float* __restrict__ WhhT,
    const float* __restrict__ W_ih, const float* __restrict__ b_ih,
    const float* __restrict__ b_hh,
    const float* __restrict__ wo, const float* __restrict__ bo_p,
    float* __restrict__ out)
{
    const int tid = threadIdx.x;
    const int bb  = blockIdx.x;
    const int jp  = tid >> 3;     // column pair 0..127
    const int e   = tid & 7;      // K-slice eighth
    const int c   = e & 1;
    const int jc  = 2 * jp + c;

    __shared__ float whh_lds[I_LDS * 768];               // 147456 B
    __shared__ __align__(16) float xsb[2][8 * XGRP];     // 2304 B
    __shared__ __align__(16) float xsf[H];               // hp (linear)
    __shared__ float gh_lds[768];
    __shared__ float red[4];
    __shared__ float times_s[T_STEPS];
    __shared__ float bv_s[T_STEPS], trm_s[T_STEPS], tem_s[T_STEPS], m_s[T_STEPS];

    // Weff tile: rows 32e..32e+31 x cols {2jp, 2jp+1}, pinned in regs
    float2 wregv[32];
    #pragma unroll
    for (int il = 0; il < 32; ++il)
        wregv[il] = *(const float2*)&Weff[(32 * e + il) * H + 2 * jp];
    #pragma unroll
    for (int il = 0; il < 32; ++il)
        asm volatile("" : "+v"(wregv[il].x), "+v"(wregv[il].y));

    // stage WhhT rows [0,I_LDS) + per-step scalars
    for (int k = tid; k < I_LDS * 768; k += 1024) whh_lds[k] = WhhT[k];
    if (tid < T_STEPS) {
        times_s[tid] = b_in[2 * tid];   // times identical across batch
        int bt = bb * T_STEPS + tid;
        bv_s[tid]  = b_in[2 * bt + 1];
        trm_s[tid] = trm_in[bt];
        tem_s[tid] = tem_in[bt];
        m_s[tid]   = m_in[bt];
    }

    float h = h0[bb * H + jc];
    const float be   = beff[jc];
    const float bihr = b_ih[jc], bihz = b_ih[H + jc], bihn = b_ih[2 * H + jc];
    const float bhhr = b_hh[jc], bhhz = b_hh[H + jc], bhhn = b_hh[2 * H + jc];
    const float wihr = W_ih[jc], wihz = W_ih[H + jc], wihn = W_ih[2 * H + jc];
    const float bo   = bo_p[0];
    const float wo_t = (tid >= 768) ? wo[tid - 768] : 0.f;

    // publish slot for this thread's column (valid when e < 2: then jc == 2jp+e)
    const int pubpos = (jc >> 5) * XGRP + (jc & 31);

    if (e < 2) xsb[0][pubpos] = h;     // initial publish (step 0 reads buf 0)
    __syncthreads();

    // eval: 8 broadcast b128 reads, 64 FMA (2 cols), 3-level xor-reduce, tanh
    #define EVAL(KOUT_) do {                                       \
        const float* xp_ = &xsb[cur][e * XGRP];                    \
        float a0_ = 0.f, a1_ = 0.f, b0_ = 0.f, b1_ = 0.f;          \
        _Pragma("unroll")                                          \
        for (int g_ = 0; g_ < 8; ++g_) {                           \
            float4 x_ = ((const float4*)xp_)[g_];                  \
            a0_ = fmaf(x_.x, wregv[4 * g_ + 0].x, a0_);            \
            b0_ = fmaf(x_.x, wregv[4 * g_ + 0].y, b0_);            \
            a1_ = fmaf(x_.y, wregv[4 * g_ + 1].x, a1_);            \
            b1_ = fmaf(x_.y, wregv[4 * g_ + 1].y, b1_);            \
            a0_ = fmaf(x_.z, wregv[4 * g_ + 2].x, a0_);            \
            b0_ = fmaf(x_.z, wregv[4 * g_ + 2].y, b0_);            \
            a1_ = fmaf(x_.w, wregv[4 * g_ + 3].x, a1_);            \
            b1_ = fmaf(x_.w, wregv[4 * g_ + 3].y, b1_);            \
        }                                                          \
        float s0_ = a0_ + a1_, s1_ = b0_ + b1_;                    \
        _Pragma("unroll")                                          \
        for (int o_ = 1; o_ < 8; o_ <<= 1) {                       \
            s0_ += __shfl_xor(s0_, o_);                            \
            s1_ += __shfl_xor(s1_, o_);                            \
        }                                                          \
        KOUT_ = tanhf(be + (c == 0 ? s0_ : s1_));                  \
    } while (0)

    // publish next matvec arg (lanes e<2, one b32 each); barrier; flip
    #define PUBLISH(V_) do {                                       \
        if (e < 2) xsb[cur ^ 1][pubpos] = (V_);                    \
        __syncthreads();                                           \
        cur ^= 1;                                                  \
    } while (0)

    float tprev = 0.f;
    #pragma unroll 1
    for (int t = 0; t < T_STEPS; ++t) {
        float t1 = times_s[t];
        float dt = (t1 - tprev) * 0.5f;   // per-substep dt (N_SUB=2)
        tprev = t1;

        int cur = 0;
        float k1, k2, k3, k4;
        #pragma unroll 1
        for (int s = 0; s < 2; ++s) {
            EVAL(k1); PUBLISH(fmaf(0.5f * dt, k1, h));
            EVAL(k2); PUBLISH(fmaf(0.5f * dt, k2, h));
            EVAL(k3); PUBLISH(fmaf(dt, k3, h));
            EVAL(k4);
            h = fmaf(dt * (1.f / 6.f), k1 + 2.f * (k2 + k3) + k4, h);
            if (s == 0) PUBLISH(h);   // substep-2 k1 reads h
        }

        // stage hp (linear) for gh + out head
        if (e < 2) xsf[jc] = h;
        __syncthreads();

        // gh = hp @ W_hh^T: rows [0,I_LDS) from LDS, rest streamed from L2.
        // (round-5 code: consecutive tids -> consecutive banks, conflict-free)
        // || out-head dot (waves 12..15)
        if (tid < 768) {
            float g0 = 0.f, g1 = 0.f, g2 = 0.f, g3 = 0.f;
            const float* wl = whh_lds + tid;
            #pragma unroll 4
            for (int i = 0; i < I_LDS; i += 4) {
                float4 xv = *(const float4*)(xsf + i);
                g0 = fmaf(xv.x, wl[(i + 0) * 768], g0);
                g1 = fmaf(xv.y, wl[(i + 1) * 768], g1);
                g2 = fmaf(xv.z, wl[(i + 2) * 768], g2);
                g3 = fmaf(xv.w, wl[(i + 3) * 768], g3);
            }
            const float* wr = WhhT + I_LDS * 768 + tid;
            #pragma unroll 8
            for (int i = 0; i < H - I_LDS; i += 4) {
                float4 xv = *(const float4*)(xsf + I_LDS + i);
                g0 = fmaf(xv.x, wr[(i + 0) * 768], g0);
                g1 = fmaf(xv.y, wr[(i + 1) * 768], g1);
                g2 = fmaf(xv.z, wr[(i + 2) * 768], g2);
                g3 = fmaf(xv.w, wr[(i + 3) * 768], g3);
            }
            gh_lds[tid] = (g0 + g1) + (g2 + g3);
        } else {
            float p = xsf[tid - 768] * wo_t;
            #pragma unroll
            for (int off = 32; off > 0; off >>= 1) p += __shfl_down(p, off);
            if ((tid & 63) == 0) red[(tid - 768) >> 6] = p;
        }
        __syncthreads();

        // gates: ALL threads compute for their jc (replicated, bit-identical)
        {
            float outv = tanhf(red[0] + red[1] + red[2] + red[3] + bo);
            float bv = bv_s[t], trm = trm_s[t], tem = tem_s[t], mv = m_s[t];
            float ghr = gh_lds[jc] + bhhr;
            float ghz = gh_lds[256 + jc] + bhhz;
            float ghn = gh_lds[512 + jc] + bhhn;
            float x1v = bv * trm, x2v = outv * tem;

            float r1 = sigmoidf_(fmaf(x1v, wihr, bihr) + ghr);
            float z1 = sigmoidf_(fmaf(x1v, wihz, bihz) + ghz);
            float n1 = tanhf(fmaf(x1v, wihn, bihn) + r1 * ghn);
            float h1 = (1.f - z1) * n1 + z1 * h;

            float r2 = sigmoidf_(fmaf(x2v, wihr, bihr) + ghr);
            float z2 = sigmoidf_(fmaf(x2v, wihz, bihz) + ghz);
            float n2 = tanhf(fmaf(x2v, wihn, bihn) + r2 * ghn);
            float h2 = (1.f - z2) * n2 + z2 * h;

            if (tid == 0) out[bb * T_STEPS + t] = outv;
            h = trm * h1 + tem * h2 + (1.f - mv) * h;
        }

        // publish h_new for next step's first eval (reads buf 0)
        if (e < 2) xsb[0][pubpos] = h;
        __syncthreads();
    }
    #undef EVAL
    #undef PUBLISH
}

// ---------------- launcher ----------------

extern "C" void kernel_launch(void* const* d_in, const int* in_sizes, int n_in,
                              void* d_out, int out_size, void* d_ws, size_t ws_size,
                              hipStream_t stream) {
    const float* b_in = (const float*)d_in[0];
    const float* m_in = (const float*)d_in[1];
    const float* trm  = (const float*)d_in[2];
    const float* tem  = (const float*)d_in[3];
    const float* h0   = (const float*)d_in[4];
    const float* W1   = (const float*)d_in[5];
    const float* b1   = (const float*)d_in[6];
    const float* W2   = (const float*)d_in[7];
    const float* b2   = (const float*)d_in[8];
    const float* W_ih = (const float*)d_in[9];
    const float* W_hh = (const float*)d_in[10];
    const float* b_ih = (const float*)d_in[11];
    const float* b_hh = (const float*)d_in[12];
    const float* Wo1  = (const float*)d_in[13];
    const float* bo1  = (const float*)d_in[14];
    const float* Wo2  = (const float*)d_in[15];
    const float* bo2  = (const float*)d_in[16];

    float* ws   = (float*)d_ws;
    float* Weff = ws;             // 65536
    float* beff = Weff + 65536;   // 256
    float* WhhT = beff + 256;     // 196608
    float* wo   = WhhT + 196608;  // 256
    float* bo   = wo + 256;       // 1

    prep_weff<<<256, 256, 0, stream>>>(W1, W2, b1, b2, Weff, beff);
    prep_whht<<<192, 1024, 0, stream>>>(W_hh, WhhT);
    prep_wo<<<1, 256, 0, stream>>>(Wo1, Wo2, bo1, bo2, wo, bo);

    ode_rnn_main<<<B_BATCH, 1024, 0, stream>>>(b_in, m_in, trm, tem, h0,
                                               Weff, beff, WhhT,
                                               W_ih, b_ih, b_hh, wo, bo,
                                               (float*)d_out);
}